// Round 6
// baseline (398.722 us; speedup 1.0000x reference)
//
#include <hip/hip_runtime.h>
#include <hip/hip_bf16.h>
#include <math.h>

#define NN   10000
#define IND  512
#define HID  256
#define NE   400000
#define KPAD 10240   // adj GEMM K padded
#define SKA  8       // split-K adj GEMM  (KCHA = 1280, nt = 40)
#define KCHA 1280
#define SKX  2       // split-K X@W GEMM  (KCHX = 256, nt = 8)
#define KCHX 256

typedef __attribute__((ext_vector_type(4))) float  f32x4;
typedef __attribute__((ext_vector_type(4))) int    i32x4;
typedef __attribute__((ext_vector_type(2))) uint   u32x2;
typedef __attribute__((ext_vector_type(8))) short  bf16x8;

static __device__ inline ushort f2b(float f) {
    union { __hip_bfloat16 b; ushort u; } c;
    c.b = __float2bfloat16(f);
    return c.u;
}
static __device__ inline float b2f(ushort u) {
    union { uint t; float f; } c;
    c.t = (uint)u << 16;
    return c.f;
}
static __device__ inline void gload_lds16(const void* g, void* l) {
    __builtin_amdgcn_global_load_lds(
        (const __attribute__((address_space(1))) unsigned int*)g,
        (__attribute__((address_space(3))) unsigned int*)l, 16, 0, 0);
}
// pinned-order A prefetch: exactly 2 vmem loads (vmcnt accounting)
static __device__ inline void aload(const float* p, f32x4& a, f32x4& b) {
    asm volatile("global_load_dwordx4 %0, %2, off\n\t"
                 "global_load_dwordx4 %1, %2, off offset:16"
                 : "=&v"(a), "=&v"(b) : "v"(p) : "memory");
}

// ---------------------------------------------------------------------------
// Transpose + convert: dst[c][r] = bf16(src[r][c]) for r<R else 0.
__global__ __launch_bounds__(256) void tr_cvt(
    const float* __restrict__ src, ushort* __restrict__ dst,
    int R, int C, int Rpad)
{
    __shared__ float t[64][65];
    const int r0 = blockIdx.x * 64, c0 = blockIdx.y * 64;
    const int tx = threadIdx.x & 63, ty = threadIdx.x >> 6;

    #pragma unroll
    for (int i = 0; i < 16; ++i) {
        const int rl = ty * 16 + i;
        const int r  = r0 + rl;
        float v = 0.f;
        if (r < R) v = src[(size_t)r * C + c0 + tx];
        t[rl][tx] = v;
    }
    __syncthreads();
    #pragma unroll
    for (int i = 0; i < 16; ++i) {
        const int cl = ty * 16 + i;
        dst[(size_t)(c0 + cl) * Rpad + r0 + tx] = f2b(t[tx][cl]);
    }
}

// ---------------------------------------------------------------------------
// C[M,256] += A[M, kbeg:kbeg+k_chunk] @ B(chunk) via atomicAdd (C pre-zeroed).
// Ring-pipelined: B staged 3 steps ahead (Blds ring-4, global_load_lds),
// A 2 steps ahead in regs -> cvt -> Alds ring-2. One counted
// "s_waitcnt vmcnt(10)" + "lgkmcnt(0)" + barrier per K-step; never drains.
__global__ __launch_bounds__(256, 2) void gemm_n256(
    const float* __restrict__ A, const ushort* __restrict__ BT,
    float* __restrict__ C, int M, int K_real, int ld_bt, int lda, int k_chunk)
{
    __shared__ ushort Alds[2][2048];   //  8 KB (ring-2)
    __shared__ ushort Blds[4][8192];   // 64 KB (ring-4)

    const int tid  = threadIdx.x;
    const int lane = tid & 63;
    const int w    = tid >> 6;

    // bijective XCD-chunk swizzle; row fastest, sk-major (one sk per XCD-ish)
    const int gx  = gridDim.x;
    const int nwg = gx * gridDim.y;
    const int lin = blockIdx.y * gx + blockIdx.x;
    const int q = nwg >> 3, r = nwg & 7;
    const int xc = lin & 7, o = lin >> 3;
    const int work = (xc < r ? xc * (q + 1) : r * (q + 1) + (xc - r) * q) + o;
    const int row0 = (work % gx) * 64;
    const int sk   = work / gx;
    const int kbeg = sk * k_chunk;

    // A staging: thread t -> slot t: rowgrp=t>>6, kgrp=(t>>4)&3, row16=t&15
    const int arow = ((tid >> 6) << 4) | (tid & 15);
    const int akg  = (tid >> 4) & 3;
    const int grow = row0 + arow;
    const bool aok = grow < M;
    const bool lastrow = (grow == M - 1);
    const float* aptr = A + (size_t)grow * lda + kbeg + (akg << 3);

    // B staging: wave w stages colgrps 4w..4w+3
    const ushort* bsrc0 = BT + (size_t)((w << 6) + (lane & 15)) * ld_bt
                             + kbeg + ((lane >> 4) << 3);

    const int nt = k_chunk >> 5;

    f32x4 acc[4][4];
    #pragma unroll
    for (int i = 0; i < 4; ++i)
        #pragma unroll
        for (int j = 0; j < 4; ++j)
            acc[i][j] = (f32x4){0.f, 0.f, 0.f, 0.f};

    // clamped A address for tile k-offset kn (always issues 2 loads)
    auto apick = [&](int kn) -> const float* {
        const bool ok = aok && (kn < k_chunk) &&
                        (!lastrow || (kbeg + kn + (akg << 3) + 8) <= K_real);
        return ok ? (aptr + kn) : A;
    };
    // issue 4 B gload_lds for tile tt into Blds[tt&3]
    auto stageB = [&](int tt) {
        const int kb = tt << 5;
        #pragma unroll
        for (int g = 0; g < 4; ++g)
            gload_lds16(bsrc0 + (size_t)(g << 4) * ld_bt + kb,
                        &Blds[tt & 3][((w << 2) + g) << 9]);
    };
    // MFMA on tile tt
    auto compute = [&](int tt) {
        const ushort* Ab = Alds[tt & 1];
        const ushort* Bb = Blds[tt & 3];
        bf16x8 bfr[4];
        #pragma unroll
        for (int nf = 0; nf < 4; ++nf)
            bfr[nf] = *reinterpret_cast<const bf16x8*>(
                &Bb[((((w << 2) + nf) << 6) | lane) << 3]);
        #pragma unroll
        for (int mf = 0; mf < 4; ++mf) {
            const bf16x8 af = *reinterpret_cast<const bf16x8*>(
                &Ab[((mf << 6) | lane) << 3]);
            #pragma unroll
            for (int nf = 0; nf < 4; ++nf)
                acc[mf][nf] = __builtin_amdgcn_mfma_f32_16x16x32_bf16(
                    af, bfr[nf], acc[mf][nf], 0, 0, 0);
        }
    };
    // cvt + ds_write A tile tt into Alds[tt&1]
    auto writeA = [&](int tt, const f32x4& x0, const f32x4& x1) {
        union { ushort u[8]; i32x4 v4; } pk;
        pk.u[0]=f2b(x0.x); pk.u[1]=f2b(x0.y); pk.u[2]=f2b(x0.z); pk.u[3]=f2b(x0.w);
        pk.u[4]=f2b(x1.x); pk.u[5]=f2b(x1.y); pk.u[6]=f2b(x1.z); pk.u[7]=f2b(x1.w);
        *reinterpret_cast<i32x4*>(&Alds[tt & 1][tid << 3]) = pk.v4;
    };
    // one steady-state step: consume A(t+1)=i, issue A(t+2)->o, B(t+3)
    auto STEP = [&](int t, f32x4& i0, f32x4& i1, f32x4& o0, f32x4& o1) {
        aload(apick((t + 2) << 5), o0, o1);
        stageB(t + 3);
        compute(t);
        asm volatile("s_waitcnt vmcnt(10)" ::: "memory");  // A(t+1) + B(t+1) done
        __builtin_amdgcn_sched_barrier(0);
        writeA(t + 1, i0, i1);
        asm volatile("s_waitcnt lgkmcnt(0)" ::: "memory");
        __builtin_amdgcn_s_barrier();
    };

    f32x4 aP0, aP1, aQ0, aQ1;
    // ---- prologue: issue order [A0, B0, B1, A1, B2] (16 outstanding) ----
    aload(apick(0), aP0, aP1);
    stageB(0);
    stageB(1);
    aload(apick(32), aQ0, aQ1);
    stageB(2);
    asm volatile("s_waitcnt vmcnt(14)" ::: "memory");      // A0 ready
    __builtin_amdgcn_sched_barrier(0);
    writeA(0, aP0, aP1);
    asm volatile("s_waitcnt vmcnt(10) lgkmcnt(0)" ::: "memory"); // B0 done
    __builtin_amdgcn_s_barrier();

    // ---- main loop (pairs, static reg parity) ----
    const int S = nt - 3;           // full-issue steps
    int t = 0;
    for (; t + 1 < S; t += 2) {
        STEP(t,     aQ0, aQ1, aP0, aP1);
        STEP(t + 1, aP0, aP1, aQ0, aQ1);
    }
    if (S & 1) {
        STEP(S - 1, aQ0, aQ1, aP0, aP1);
        // E1: consume aP = A(nt-2), issue A(nt-1) -> aQ
        aload(apick((nt - 1) << 5), aQ0, aQ1);
        compute(nt - 3);
        asm volatile("s_waitcnt vmcnt(6)" ::: "memory");
        __builtin_amdgcn_sched_barrier(0);
        writeA(nt - 2, aP0, aP1);
        asm volatile("s_waitcnt lgkmcnt(0)" ::: "memory");
        __builtin_amdgcn_s_barrier();
        // E2: consume aQ = A(nt-1)
        compute(nt - 2);
        asm volatile("s_waitcnt vmcnt(0)" ::: "memory");
        __builtin_amdgcn_sched_barrier(0);
        writeA(nt - 1, aQ0, aQ1);
        asm volatile("s_waitcnt lgkmcnt(0)" ::: "memory");
        __builtin_amdgcn_s_barrier();
        compute(nt - 1);
    } else {
        // E1: consume aQ = A(nt-2), issue A(nt-1) -> aP
        aload(apick((nt - 1) << 5), aP0, aP1);
        compute(nt - 3);
        asm volatile("s_waitcnt vmcnt(6)" ::: "memory");
        __builtin_amdgcn_sched_barrier(0);
        writeA(nt - 2, aQ0, aQ1);
        asm volatile("s_waitcnt lgkmcnt(0)" ::: "memory");
        __builtin_amdgcn_s_barrier();
        compute(nt - 2);
        asm volatile("s_waitcnt vmcnt(0)" ::: "memory");
        __builtin_amdgcn_sched_barrier(0);
        writeA(nt - 1, aP0, aP1);
        asm volatile("s_waitcnt lgkmcnt(0)" ::: "memory");
        __builtin_amdgcn_s_barrier();
        compute(nt - 1);
    }

    // epilogue: atomic accumulate; col = lane&15, row = base + (lane>>4)*4 + rr
    #pragma unroll
    for (int mf = 0; mf < 4; ++mf) {
        const int rbase = row0 + mf * 16 + ((lane >> 4) << 2);
        #pragma unroll
        for (int nf = 0; nf < 4; ++nf) {
            const int col = (w << 6) + nf * 16 + (lane & 15);
            #pragma unroll
            for (int rr = 0; rr < 4; ++rr) {
                const int row = rbase + rr;
                if (row < M) atomicAdd(&C[(size_t)row * HID + col], acc[mf][nf][rr]);
            }
        }
    }
}

// ---------------------------------------------------------------------------
__global__ void k_uv(const float* __restrict__ W2, const float* __restrict__ W3,
                     float* __restrict__ c)
{
    const int j = blockIdx.x * blockDim.x + threadIdx.x;
    if (j >= 2 * HID) return;
    float s = 0.f;
    for (int m = 0; m < HID; ++m)
        s = fmaf(W2[(size_t)j * HID + m], W3[m], s);
    c[j] = s;
}

// ---------------------------------------------------------------------------
__global__ __launch_bounds__(256) void k_node(
    const float* __restrict__ z, const float* __restrict__ c,
    const float* __restrict__ W3, ushort* __restrict__ zb,
    ushort* __restrict__ zsb, float* __restrict__ av, float* __restrict__ bv)
{
    const int node = (int)((blockIdx.x * blockDim.x + threadIdx.x) >> 6);
    const int lane = threadIdx.x & 63;
    if (node >= NN) return;

    const f32x4 s = *reinterpret_cast<const f32x4*>(&z[(size_t)node * HID + (lane << 2)]);
    const f32x4 w4 = *reinterpret_cast<const f32x4*>(&W3[HID + (lane << 2)]);
    const f32x4 u4 = *reinterpret_cast<const f32x4*>(&c[(lane << 2)]);
    const f32x4 v4 = *reinterpret_cast<const f32x4*>(&c[HID + (lane << 2)]);
    const f32x4 zs4 = s * w4;

    union { ushort u[4]; u32x2 v; } pz, ps;
    pz.u[0] = f2b(s.x);   pz.u[1] = f2b(s.y);
    pz.u[2] = f2b(s.z);   pz.u[3] = f2b(s.w);
    ps.u[0] = f2b(zs4.x); ps.u[1] = f2b(zs4.y);
    ps.u[2] = f2b(zs4.z); ps.u[3] = f2b(zs4.w);
    *reinterpret_cast<u32x2*>(&zb [(size_t)node * HID + (lane << 2)]) = pz.v;
    *reinterpret_cast<u32x2*>(&zsb[(size_t)node * HID + (lane << 2)]) = ps.v;

    const float r0 = fmaxf(s.x, 0.f), r1 = fmaxf(s.y, 0.f);
    const float r2 = fmaxf(s.z, 0.f), r3 = fmaxf(s.w, 0.f);
    float pa = r0 * u4.x + r1 * u4.y + r2 * u4.z + r3 * u4.w;
    float pb = r0 * v4.x + r1 * v4.y + r2 * v4.z + r3 * v4.w;

    #pragma unroll
    for (int off = 32; off; off >>= 1) {
        pa += __shfl_down(pa, off);
        pb += __shfl_down(pb, off);
    }
    if (lane == 0) { av[node] = pa; bv[node] = pb; }
}

// ---------------------------------------------------------------------------
__global__ __launch_bounds__(256) void k_edge(
    const int* __restrict__ e1, const int* __restrict__ e2,
    const ushort* __restrict__ zb, const ushort* __restrict__ zsb,
    const float* __restrict__ av, const float* __restrict__ bv,
    float* __restrict__ out)
{
    const long long wid = (((long long)blockIdx.x * blockDim.x) + threadIdx.x) >> 6;
    const int lane = threadIdx.x & 63;
    const int half = lane >> 5;
    const int l32  = lane & 31;
    const long long e = 2LL * wid + half;
    if (e >= 2LL * NE) return;

    const int* ep = (e < NE) ? &e1[2 * (int)e] : &e2[2 * ((int)e - NE)];
    const int i = ep[0];
    const int j = ep[1];

    const bf16x8 zi = *reinterpret_cast<const bf16x8*>(&zsb[(size_t)i * HID + (l32 << 3)]);
    const bf16x8 zj = *reinterpret_cast<const bf16x8*>(&zb [(size_t)j * HID + (l32 << 3)]);
    float p = 0.f;
    #pragma unroll
    for (int t = 0; t < 8; ++t)
        p = fmaf(b2f((ushort)zi[t]), b2f((ushort)zj[t]), p);

    #pragma unroll
    for (int m = 16; m; m >>= 1)
        p += __shfl_xor(p, m);

    if (l32 == 0) {
        const float logit = av[i] + bv[j] + p;
        out[e] = 1.f / (1.f + expf(-logit));
    }
}

// ---------------------------------------------------------------------------
extern "C" void kernel_launch(void* const* d_in, const int* in_sizes, int n_in,
                              void* d_out, int out_size, void* d_ws, size_t ws_size,
                              hipStream_t stream)
{
    const float* X   = (const float*)d_in[0];
    const float* adj = (const float*)d_in[1];
    const int*   e1  = (const int*)d_in[2];
    const int*   e2  = (const int*)d_in[3];
    const float* W   = (const float*)d_in[4];
    const float* W2  = (const float*)d_in[5];
    const float* W3  = (const float*)d_in[6];
    float* out = (float*)d_out;

    float*  ws   = (float*)d_ws;
    float*  a    = ws;                                   // NN
    float*  b    = a + NN;                               // NN
    float*  c    = b + NN;                               // 512
    float*  XW   = c + 512;                              // NN*HID f32
    float*  z    = XW + (size_t)NN * HID;                // NN*HID f32
    ushort* WTb  = (ushort*)(z + (size_t)NN * HID);      // HID*IND
    ushort* XWbT = WTb  + (size_t)HID * IND;             // HID*KPAD
    ushort* zb   = XWbT + (size_t)HID * KPAD;            // NN*HID
    ushort* zsb  = zb   + (size_t)NN * HID;              // NN*HID

    const dim3 blk(256);

    hipMemsetAsync(XW, 0, (size_t)NN * HID * 4, stream);
    hipMemsetAsync(z,  0, (size_t)NN * HID * 4, stream);

    tr_cvt<<<dim3(IND / 64, HID / 64), blk, 0, stream>>>(W, WTb, IND, HID, IND);

    gemm_n256<<<dim3(157, SKX), blk, 0, stream>>>(X, WTb, XW, NN, IND, IND, IND, KCHX);

    tr_cvt<<<dim3(KPAD / 64, HID / 64), blk, 0, stream>>>(XW, XWbT, NN, HID, KPAD);

    gemm_n256<<<dim3(157, SKA), blk, 0, stream>>>(adj, XWbT, z, NN, NN, KPAD, NN, KCHA);

    k_uv<<<dim3(2), blk, 0, stream>>>(W2, W3, c);

    k_node<<<dim3((NN * 64) / 256), blk, 0, stream>>>(z, c, W3, zb, zsb, a, b);

    k_edge<<<dim3((NE * 64) / 256), blk, 0, stream>>>(e1, e2, zb, zsb, a, b, out);
}

// Round 7
// 348.147 us; speedup vs baseline: 1.1453x; 1.1453x over previous
//
#include <hip/hip_runtime.h>
#include <hip/hip_bf16.h>
#include <math.h>

#define NN   10000
#define IND  512
#define HID  256
#define NE   400000
#define KPAD 10240   // adj GEMM K padded (320 panels of 32)
#define SKA  8       // adj split-K: k_chunk 1280, nt 40
#define KCHA 1280
#define SKX  4       // X@W split-K: k_chunk 128, nt 4
#define KCHX 128
#define BM   128

typedef __attribute__((ext_vector_type(4))) float  f32x4;
typedef __attribute__((ext_vector_type(4))) int    i32x4;
typedef __attribute__((ext_vector_type(2))) uint   u32x2;
typedef __attribute__((ext_vector_type(8))) short  bf16x8;

static __device__ inline ushort f2b(float f) {
    union { __hip_bfloat16 b; ushort u; } c;
    c.b = __float2bfloat16(f);
    return c.u;
}
static __device__ inline float b2f(ushort u) {
    union { uint t; float f; } c;
    c.t = (uint)u << 16;
    return c.f;
}
static __device__ inline void gload_lds16(const void* g, void* l) {
    __builtin_amdgcn_global_load_lds(
        (const __attribute__((address_space(1))) unsigned int*)g,
        (__attribute__((address_space(3))) unsigned int*)l, 16, 0, 0);
}
// pinned-order A prefetch: exactly 2 vmem loads (vmcnt accounting)
static __device__ inline void aload(const float* p, f32x4& a, f32x4& b) {
    asm volatile("global_load_dwordx4 %0, %2, off\n\t"
                 "global_load_dwordx4 %1, %2, off offset:16"
                 : "=&v"(a), "=&v"(b) : "v"(p) : "memory");
}

// ---------------------------------------------------------------------------
// Emit K-step panels: panel p covers k in [32p, 32p+32), 16 KB each.
// Panel linear order == GEMM LDS fragment order:
//   slot s (16 B) : g = s>>6, l = s&63  ->  B[col = g*16 + (l&15)][k8 = l>>4]
// src is [R][256] f32 (row r = k). Rows >= R produce zeros.
__global__ __launch_bounds__(256) void cvt_tiled(
    const float* __restrict__ src, ushort* __restrict__ dst, int R)
{
    __shared__ float t[32][256];
    const int p   = blockIdx.x;
    const int tid = threadIdx.x;
    const int r0  = p << 5;

    #pragma unroll
    for (int j = 0; j < 8; ++j) {
        const int f   = (j << 8) + tid;       // float4 index 0..2047
        const int row = f >> 6;
        const int c4  = (f & 63) << 2;
        f32x4 v = {0.f, 0.f, 0.f, 0.f};
        if (r0 + row < R)
            v = *reinterpret_cast<const f32x4*>(&src[(size_t)(r0 + row) * 256 + c4]);
        *reinterpret_cast<f32x4*>(&t[row][c4]) = v;
    }
    __syncthreads();

    #pragma unroll
    for (int qq = 0; qq < 4; ++qq) {
        const int s   = (qq << 8) + tid;      // slot 0..1023
        const int g   = s >> 6, l = s & 63;
        const int col = (g << 4) + (l & 15);
        const int k8  = (l >> 4) << 3;
        union { ushort u[8]; i32x4 v4; } pk;
        #pragma unroll
        for (int i = 0; i < 8; ++i) pk.u[i] = f2b(t[k8 + i][col]);
        *reinterpret_cast<i32x4*>(&dst[((size_t)p << 13) + ((size_t)s << 3)]) = pk.v4;
    }
}

// ---------------------------------------------------------------------------
// C[M,256] += A[M, kbeg:kbeg+k_chunk] @ B(chunk) via atomicAdd (C pre-zeroed).
// A f32 (cvt bf16 on the fly, reg->LDS), B pre-tiled bf16 panels (16 KB/step,
// staged via contiguous 1 KB global_load_lds). 128x256 block, 8 waves (2x4),
// wave tile 64x64, BK=32, LDS dbuf, counted vmcnt per step.
__global__ __launch_bounds__(512, 4) void gemm_bt(
    const float* __restrict__ A, const ushort* __restrict__ BT2,
    float* __restrict__ C, int M, int K_real, int lda, int k_chunk)
{
    __shared__ ushort Alds[2][4096];   // 128x32 bf16, 8 KB per buf
    __shared__ ushort Blds[2][8192];   // 16 KB per buf

    const int tid  = threadIdx.x;      // 0..511
    const int lane = tid & 63;
    const int w    = tid >> 6;         // wave 0..7
    const int wm   = w >> 2;           // row half 0..1
    const int wn   = w & 3;            // col quadrant 0..3

    // bijective XCD-chunk swizzle; row fastest, sk-major (632=79*8 -> 1 sk/XCD)
    const int gx  = gridDim.x;
    const int nwg = gx * gridDim.y;
    const int lin = blockIdx.y * gx + blockIdx.x;
    const int q = nwg >> 3, r = nwg & 7;
    const int xc = lin & 7, o = lin >> 3;
    const int work = (xc < r ? xc * (q + 1) : r * (q + 1) + (xc - r) * q) + o;
    const int row0 = (work % gx) * BM;
    const int sk   = work / gx;
    const int kbeg = sk * k_chunk;

    // A staging: thread t -> (row t>>2, kgroup t&3); LDS slot = inverse frag map
    const int arow = tid >> 2;                    // 0..127
    const int akg  = tid & 3;                     // 0..3 (8 floats each)
    const int grow = row0 + arow;
    const bool aok = grow < M;
    const bool lastrow = (grow == M - 1);
    const float* aptr = A + (size_t)grow * lda + kbeg + (akg << 3);
    const int aslot = ((arow >> 4) << 6) | (akg << 4) | (arow & 15);

    const int nt = k_chunk >> 5;

    f32x4 acc[4][4];
    #pragma unroll
    for (int i = 0; i < 4; ++i)
        #pragma unroll
        for (int j = 0; j < 4; ++j)
            acc[i][j] = (f32x4){0.f, 0.f, 0.f, 0.f};

    // clamped A address (always issues 2 loads -> uniform vmcnt)
    auto apick = [&](int kn) -> const float* {
        const bool ok = aok && (kn < k_chunk) &&
                        (!lastrow || (kbeg + kn + (akg << 3) + 8) <= K_real);
        return ok ? (aptr + kn) : A;
    };
    // stage B panel (kbeg/32 + t) into Blds[buf]: 2 contiguous 1 KB gloads/wave
    auto stageB = [&](int t, int buf) {
        const ushort* ps = BT2 + (((size_t)(kbeg >> 5) + t) << 13) + ((w << 1) << 9);
        gload_lds16(ps,       &Blds[buf][(w << 1) << 9]);
        gload_lds16(ps + 512, &Blds[buf][((w << 1) + 1) << 9]);
    };
    auto writeA = [&](int buf, const f32x4& x0, const f32x4& x1) {
        union { ushort u[8]; i32x4 v4; } pk;
        pk.u[0]=f2b(x0.x); pk.u[1]=f2b(x0.y); pk.u[2]=f2b(x0.z); pk.u[3]=f2b(x0.w);
        pk.u[4]=f2b(x1.x); pk.u[5]=f2b(x1.y); pk.u[6]=f2b(x1.z); pk.u[7]=f2b(x1.w);
        *reinterpret_cast<i32x4*>(&Alds[buf][aslot << 3]) = pk.v4;
    };
    auto compute = [&](int buf) {
        bf16x8 bfr[4];
        #pragma unroll
        for (int nf = 0; nf < 4; ++nf)
            bfr[nf] = *reinterpret_cast<const bf16x8*>(
                &Blds[buf][((((wn << 2) + nf) << 6) | lane) << 3]);
        #pragma unroll
        for (int mf = 0; mf < 4; ++mf) {
            const bf16x8 af = *reinterpret_cast<const bf16x8*>(
                &Alds[buf][((((wm << 2) + mf) << 6) | lane) << 3]);
            #pragma unroll
            for (int nf = 0; nf < 4; ++nf)
                acc[mf][nf] = __builtin_amdgcn_mfma_f32_16x16x32_bf16(
                    af, bfr[nf], acc[mf][nf], 0, 0, 0);
        }
    };

    f32x4 va0, va1;
    // ---- prologue: stage tile 0 ----
    aload(apick(0), va0, va1);
    stageB(0, 0);
    asm volatile("s_waitcnt vmcnt(2)" ::: "memory");   // A0 regs ready
    __builtin_amdgcn_sched_barrier(0);
    writeA(0, va0, va1);
    asm volatile("s_waitcnt vmcnt(0) lgkmcnt(0)" ::: "memory");
    __builtin_amdgcn_s_barrier();

    // ---- main loop: compute tile t, stage tile t+1 ----
    for (int t = 0; t < nt; ++t) {
        const int cur = t & 1;
        const bool more = (t + 1) < nt;
        if (more) {
            aload(apick((t + 1) << 5), va0, va1);
            stageB(t + 1, cur ^ 1);
        }
        compute(cur);
        if (more) {
            asm volatile("s_waitcnt vmcnt(2)" ::: "memory");  // A(t+1) regs
            __builtin_amdgcn_sched_barrier(0);
            writeA(cur ^ 1, va0, va1);
            asm volatile("s_waitcnt vmcnt(0) lgkmcnt(0)" ::: "memory");
            __builtin_amdgcn_s_barrier();
        }
    }

    // epilogue: atomic accumulate; col = lane&15, row = (lane>>4)*4 + rr
    #pragma unroll
    for (int mf = 0; mf < 4; ++mf) {
        const int rbase = row0 + (wm << 6) + mf * 16 + ((lane >> 4) << 2);
        #pragma unroll
        for (int nf = 0; nf < 4; ++nf) {
            const int col = (wn << 6) + nf * 16 + (lane & 15);
            #pragma unroll
            for (int rr = 0; rr < 4; ++rr) {
                const int row = rbase + rr;
                if (row < M) atomicAdd(&C[(size_t)row * HID + col], acc[mf][nf][rr]);
            }
        }
    }
}

// ---------------------------------------------------------------------------
__global__ void k_uv(const float* __restrict__ W2, const float* __restrict__ W3,
                     float* __restrict__ c)
{
    const int j = blockIdx.x * blockDim.x + threadIdx.x;
    if (j >= 2 * HID) return;
    float s = 0.f;
    for (int m = 0; m < HID; ++m)
        s = fmaf(W2[(size_t)j * HID + m], W3[m], s);
    c[j] = s;
}

// ---------------------------------------------------------------------------
__global__ __launch_bounds__(256) void k_node(
    const float* __restrict__ z, const float* __restrict__ c,
    const float* __restrict__ W3, ushort* __restrict__ zb,
    ushort* __restrict__ zsb, float* __restrict__ av, float* __restrict__ bv)
{
    const int node = (int)((blockIdx.x * blockDim.x + threadIdx.x) >> 6);
    const int lane = threadIdx.x & 63;
    if (node >= NN) return;

    const f32x4 s = *reinterpret_cast<const f32x4*>(&z[(size_t)node * HID + (lane << 2)]);
    const f32x4 w4 = *reinterpret_cast<const f32x4*>(&W3[HID + (lane << 2)]);
    const f32x4 u4 = *reinterpret_cast<const f32x4*>(&c[(lane << 2)]);
    const f32x4 v4 = *reinterpret_cast<const f32x4*>(&c[HID + (lane << 2)]);
    const f32x4 zs4 = s * w4;

    union { ushort u[4]; u32x2 v; } pz, ps;
    pz.u[0] = f2b(s.x);   pz.u[1] = f2b(s.y);
    pz.u[2] = f2b(s.z);   pz.u[3] = f2b(s.w);
    ps.u[0] = f2b(zs4.x); ps.u[1] = f2b(zs4.y);
    ps.u[2] = f2b(zs4.z); ps.u[3] = f2b(zs4.w);
    *reinterpret_cast<u32x2*>(&zb [(size_t)node * HID + (lane << 2)]) = pz.v;
    *reinterpret_cast<u32x2*>(&zsb[(size_t)node * HID + (lane << 2)]) = ps.v;

    const float r0 = fmaxf(s.x, 0.f), r1 = fmaxf(s.y, 0.f);
    const float r2 = fmaxf(s.z, 0.f), r3 = fmaxf(s.w, 0.f);
    float pa = r0 * u4.x + r1 * u4.y + r2 * u4.z + r3 * u4.w;
    float pb = r0 * v4.x + r1 * v4.y + r2 * v4.z + r3 * v4.w;

    #pragma unroll
    for (int off = 32; off; off >>= 1) {
        pa += __shfl_down(pa, off);
        pb += __shfl_down(pb, off);
    }
    if (lane == 0) { av[node] = pa; bv[node] = pb; }
}

// ---------------------------------------------------------------------------
__global__ __launch_bounds__(256) void k_edge(
    const int* __restrict__ e1, const int* __restrict__ e2,
    const ushort* __restrict__ zb, const ushort* __restrict__ zsb,
    const float* __restrict__ av, const float* __restrict__ bv,
    float* __restrict__ out)
{
    const long long wid = (((long long)blockIdx.x * blockDim.x) + threadIdx.x) >> 6;
    const int lane = threadIdx.x & 63;
    const int half = lane >> 5;
    const int l32  = lane & 31;
    const long long e = 2LL * wid + half;
    if (e >= 2LL * NE) return;

    const int* ep = (e < NE) ? &e1[2 * (int)e] : &e2[2 * ((int)e - NE)];
    const int i = ep[0];
    const int j = ep[1];

    const bf16x8 zi = *reinterpret_cast<const bf16x8*>(&zsb[(size_t)i * HID + (l32 << 3)]);
    const bf16x8 zj = *reinterpret_cast<const bf16x8*>(&zb [(size_t)j * HID + (l32 << 3)]);
    float p = 0.f;
    #pragma unroll
    for (int t = 0; t < 8; ++t)
        p = fmaf(b2f((ushort)zi[t]), b2f((ushort)zj[t]), p);

    #pragma unroll
    for (int m = 16; m; m >>= 1)
        p += __shfl_xor(p, m);

    if (l32 == 0) {
        const float logit = av[i] + bv[j] + p;
        out[e] = 1.f / (1.f + expf(-logit));
    }
}

// ---------------------------------------------------------------------------
extern "C" void kernel_launch(void* const* d_in, const int* in_sizes, int n_in,
                              void* d_out, int out_size, void* d_ws, size_t ws_size,
                              hipStream_t stream)
{
    const float* X   = (const float*)d_in[0];
    const float* adj = (const float*)d_in[1];
    const int*   e1  = (const int*)d_in[2];
    const int*   e2  = (const int*)d_in[3];
    const float* W   = (const float*)d_in[4];
    const float* W2  = (const float*)d_in[5];
    const float* W3  = (const float*)d_in[6];
    float* out = (float*)d_out;

    float*  ws   = (float*)d_ws;
    float*  a    = ws;                                   // NN
    float*  b    = a + NN;                               // NN
    float*  c    = b + NN;                               // 512
    float*  XW   = c + 512;                              // NN*HID f32
    float*  z    = XW + (size_t)NN * HID;                // NN*HID f32
    ushort* Wt2  = (ushort*)(z + (size_t)NN * HID);      // 16 panels * 8192
    ushort* XWt2 = Wt2  + (size_t)16 * 8192;             // 320 panels * 8192
    ushort* zb   = XWt2 + (size_t)320 * 8192;            // NN*HID
    ushort* zsb  = zb   + (size_t)NN * HID;              // NN*HID

    const dim3 blk(256);

    hipMemsetAsync(XW, 0, (size_t)NN * HID * 4, stream);
    hipMemsetAsync(z,  0, (size_t)NN * HID * 4, stream);

    // W -> tiled bf16 panels (K=512 -> 16 panels)
    cvt_tiled<<<dim3(16), blk, 0, stream>>>(W, Wt2, IND);

    // XW += X @ W  (split-K = 4, atomic)
    gemm_bt<<<dim3(79, SKX), dim3(512), 0, stream>>>(X, Wt2, XW, NN, IND, IND, KCHX);

    // XW -> tiled bf16 panels (KPAD=10240 -> 320 panels, zero-padded)
    cvt_tiled<<<dim3(KPAD / 32), blk, 0, stream>>>(XW, XWt2, NN);

    // z += adj @ XW  (split-K = 8, atomic)
    gemm_bt<<<dim3(79, SKA), dim3(512), 0, stream>>>(adj, XWt2, z, NN, NN, NN, KCHA);

    // c = [u; v]
    k_uv<<<dim3(2), blk, 0, stream>>>(W2, W3, c);

    // per-node tables
    k_node<<<dim3((NN * 64) / 256), blk, 0, stream>>>(z, c, W3, zb, zsb, a, b);

    // per-edge output
    k_edge<<<dim3((NE * 64) / 256), blk, 0, stream>>>(e1, e2, zb, zsb, a, b, out);
}

// Round 8
// 303.807 us; speedup vs baseline: 1.3124x; 1.1459x over previous
//
#include <hip/hip_runtime.h>
#include <hip/hip_bf16.h>
#include <math.h>

#define NN   10000
#define IND  512
#define HID  256
#define NE   400000
#define KPAD 10240   // adj GEMM K padded (320 panels of 32)
#define SKA  8       // adj split-K: k_chunk 1280, nt 40
#define KCHA 1280
#define SKX  4       // X@W split-K: k_chunk 128, nt 4
#define KCHX 128
#define BM   128

typedef __attribute__((ext_vector_type(4))) float  f32x4;
typedef __attribute__((ext_vector_type(4))) int    i32x4;
typedef __attribute__((ext_vector_type(2))) uint   u32x2;
typedef __attribute__((ext_vector_type(8))) short  bf16x8;

static __device__ inline ushort f2b(float f) {
    union { __hip_bfloat16 b; ushort u; } c;
    c.b = __float2bfloat16(f);
    return c.u;
}
static __device__ inline float b2f(ushort u) {
    union { uint t; float f; } c;
    c.t = (uint)u << 16;
    return c.f;
}
static __device__ inline void gload_lds16(const void* g, void* l) {
    __builtin_amdgcn_global_load_lds(
        (const __attribute__((address_space(1))) unsigned int*)g,
        (__attribute__((address_space(3))) unsigned int*)l, 16, 0, 0);
}
// pinned-order A prefetch: exactly 2 vmem loads (vmcnt accounting)
static __device__ inline void aload(const float* p, f32x4& a, f32x4& b) {
    asm volatile("global_load_dwordx4 %0, %2, off\n\t"
                 "global_load_dwordx4 %1, %2, off offset:16"
                 : "=&v"(a), "=&v"(b) : "v"(p) : "memory");
}

// ---------------------------------------------------------------------------
// Emit K-step panels with optional partial-sum reduce over nparts:
// panel p covers k in [32p, 32p+32), 16 KB each; source row r = k:
//   val(r, c) = sum_q src[q*pstride + r*256 + c]   (r < R, else 0)
// Panel linear order == GEMM LDS fragment order:
//   slot s (16 B): g = s>>6, l = s&63 -> B[col = g*16 + (l&15)][k8 = l>>4]
__global__ __launch_bounds__(256) void cvt_tiled(
    const float* __restrict__ src, ushort* __restrict__ dst, int R,
    int nparts, size_t pstride)
{
    __shared__ float t[32][256];
    const int p   = blockIdx.x;
    const int tid = threadIdx.x;
    const int r0  = p << 5;

    #pragma unroll
    for (int j = 0; j < 8; ++j) {
        const int f   = (j << 8) + tid;       // float4 index 0..2047
        const int row = f >> 6;
        const int c4  = (f & 63) << 2;
        f32x4 v = {0.f, 0.f, 0.f, 0.f};
        if (r0 + row < R) {
            const float* sp = src + (size_t)(r0 + row) * 256 + c4;
            for (int qq = 0; qq < nparts; ++qq)
                v += *reinterpret_cast<const f32x4*>(sp + qq * pstride);
        }
        *reinterpret_cast<f32x4*>(&t[row][c4]) = v;
    }
    __syncthreads();

    #pragma unroll
    for (int qq = 0; qq < 4; ++qq) {
        const int s   = (qq << 8) + tid;      // slot 0..1023
        const int g   = s >> 6, l = s & 63;
        const int col = (g << 4) + (l & 15);
        const int k8  = (l >> 4) << 3;
        union { ushort u[8]; i32x4 v4; } pk;
        #pragma unroll
        for (int i = 0; i < 8; ++i) pk.u[i] = f2b(t[k8 + i][col]);
        *reinterpret_cast<i32x4*>(&dst[((size_t)p << 13) + ((size_t)s << 3)]) = pk.v4;
    }
}

// ---------------------------------------------------------------------------
// Cpart[sk][M,256] = A[M, kbeg:kbeg+k_chunk] @ B(chunk), direct store.
// A f32 (cvt bf16 on the fly, reg->LDS), B pre-tiled bf16 panels (16 KB/step,
// staged via contiguous 1 KB global_load_lds). 128x256 block, 8 waves (2x4),
// wave tile 64x64, BK=32, LDS dbuf, counted vmcnt per step.
__global__ __launch_bounds__(512, 4) void gemm_bt(
    const float* __restrict__ A, const ushort* __restrict__ BT2,
    float* __restrict__ C, int M, int K_real, int lda, int k_chunk,
    size_t c_stride)
{
    __shared__ ushort Alds[2][4096];   // 128x32 bf16, 8 KB per buf
    __shared__ ushort Blds[2][8192];   // 16 KB per buf

    const int tid  = threadIdx.x;      // 0..511
    const int lane = tid & 63;
    const int w    = tid >> 6;         // wave 0..7
    const int wm   = w >> 2;           // row half 0..1
    const int wn   = w & 3;            // col quadrant 0..3

    // bijective XCD-chunk swizzle; row fastest, sk-major (632=79*8 -> 1 sk/XCD)
    const int gx  = gridDim.x;
    const int nwg = gx * gridDim.y;
    const int lin = blockIdx.y * gx + blockIdx.x;
    const int q = nwg >> 3, r = nwg & 7;
    const int xc = lin & 7, o = lin >> 3;
    const int work = (xc < r ? xc * (q + 1) : r * (q + 1) + (xc - r) * q) + o;
    const int row0 = (work % gx) * BM;
    const int sk   = work / gx;
    const int kbeg = sk * k_chunk;
    C += (size_t)sk * c_stride;

    // A staging: thread t -> (row t>>2, kgroup t&3); LDS slot = inverse frag map
    const int arow = tid >> 2;                    // 0..127
    const int akg  = tid & 3;                     // 0..3 (8 floats each)
    const int grow = row0 + arow;
    const bool aok = grow < M;
    const bool lastrow = (grow == M - 1);
    const float* aptr = A + (size_t)grow * lda + kbeg + (akg << 3);
    const int aslot = ((arow >> 4) << 6) | (akg << 4) | (arow & 15);

    const int nt = k_chunk >> 5;

    f32x4 acc[4][4];
    #pragma unroll
    for (int i = 0; i < 4; ++i)
        #pragma unroll
        for (int j = 0; j < 4; ++j)
            acc[i][j] = (f32x4){0.f, 0.f, 0.f, 0.f};

    // clamped A address (always issues 2 loads -> uniform vmcnt)
    auto apick = [&](int kn) -> const float* {
        const bool ok = aok && (kn < k_chunk) &&
                        (!lastrow || (kbeg + kn + (akg << 3) + 8) <= K_real);
        return ok ? (aptr + kn) : A;
    };
    // stage B panel (kbeg/32 + t) into Blds[buf]: 2 contiguous 1 KB gloads/wave
    auto stageB = [&](int t, int buf) {
        const ushort* ps = BT2 + (((size_t)(kbeg >> 5) + t) << 13) + ((w << 1) << 9);
        gload_lds16(ps,       &Blds[buf][(w << 1) << 9]);
        gload_lds16(ps + 512, &Blds[buf][((w << 1) + 1) << 9]);
    };
    auto writeA = [&](int buf, const f32x4& x0, const f32x4& x1) {
        union { ushort u[8]; i32x4 v4; } pk;
        pk.u[0]=f2b(x0.x); pk.u[1]=f2b(x0.y); pk.u[2]=f2b(x0.z); pk.u[3]=f2b(x0.w);
        pk.u[4]=f2b(x1.x); pk.u[5]=f2b(x1.y); pk.u[6]=f2b(x1.z); pk.u[7]=f2b(x1.w);
        *reinterpret_cast<i32x4*>(&Alds[buf][aslot << 3]) = pk.v4;
    };
    auto compute = [&](int buf) {
        bf16x8 bfr[4];
        #pragma unroll
        for (int nf = 0; nf < 4; ++nf)
            bfr[nf] = *reinterpret_cast<const bf16x8*>(
                &Blds[buf][((((wn << 2) + nf) << 6) | lane) << 3]);
        #pragma unroll
        for (int mf = 0; mf < 4; ++mf) {
            const bf16x8 af = *reinterpret_cast<const bf16x8*>(
                &Alds[buf][((((wm << 2) + mf) << 6) | lane) << 3]);
            #pragma unroll
            for (int nf = 0; nf < 4; ++nf)
                acc[mf][nf] = __builtin_amdgcn_mfma_f32_16x16x32_bf16(
                    af, bfr[nf], acc[mf][nf], 0, 0, 0);
        }
    };

    f32x4 va0, va1;
    // ---- prologue: stage tile 0 ----
    aload(apick(0), va0, va1);
    stageB(0, 0);
    asm volatile("s_waitcnt vmcnt(2)" ::: "memory");   // A0 regs ready
    __builtin_amdgcn_sched_barrier(0);
    writeA(0, va0, va1);
    asm volatile("s_waitcnt vmcnt(0) lgkmcnt(0)" ::: "memory");
    __builtin_amdgcn_s_barrier();

    // ---- main loop: compute tile t, stage tile t+1 ----
    for (int t = 0; t < nt; ++t) {
        const int cur = t & 1;
        const bool more = (t + 1) < nt;
        if (more) {
            aload(apick((t + 1) << 5), va0, va1);
            stageB(t + 1, cur ^ 1);
        }
        compute(cur);
        if (more) {
            asm volatile("s_waitcnt vmcnt(2)" ::: "memory");  // A(t+1) regs
            __builtin_amdgcn_sched_barrier(0);
            writeA(cur ^ 1, va0, va1);
            asm volatile("s_waitcnt vmcnt(0) lgkmcnt(0)" ::: "memory");
            __builtin_amdgcn_s_barrier();
        }
    }

    // epilogue: direct store; col = lane&15, row = (lane>>4)*4 + rr
    #pragma unroll
    for (int mf = 0; mf < 4; ++mf) {
        const int rbase = row0 + (wm << 6) + mf * 16 + ((lane >> 4) << 2);
        #pragma unroll
        for (int nf = 0; nf < 4; ++nf) {
            const int col = (wn << 6) + nf * 16 + (lane & 15);
            #pragma unroll
            for (int rr = 0; rr < 4; ++rr) {
                const int row = rbase + rr;
                if (row < M) C[(size_t)row * HID + col] = acc[mf][nf][rr];
            }
        }
    }
}

// ---------------------------------------------------------------------------
__global__ void k_uv(const float* __restrict__ W2, const float* __restrict__ W3,
                     float* __restrict__ c)
{
    const int j = blockIdx.x * blockDim.x + threadIdx.x;
    if (j >= 2 * HID) return;
    float s = 0.f;
    for (int m = 0; m < HID; ++m)
        s = fmaf(W2[(size_t)j * HID + m], W3[m], s);
    c[j] = s;
}

// ---------------------------------------------------------------------------
// Reduce SKA partials + per-node tables (bf16) + a,b scalars
__global__ __launch_bounds__(256) void k_node(
    const float* __restrict__ Cpart, const float* __restrict__ c,
    const float* __restrict__ W3, ushort* __restrict__ zb,
    ushort* __restrict__ zsb, float* __restrict__ av, float* __restrict__ bv)
{
    const int node = (int)((blockIdx.x * blockDim.x + threadIdx.x) >> 6);
    const int lane = threadIdx.x & 63;
    if (node >= NN) return;

    const float* p0 = Cpart + (size_t)node * HID + (lane << 2);
    f32x4 s = *reinterpret_cast<const f32x4*>(p0);
    #pragma unroll
    for (int p = 1; p < SKA; ++p)
        s += *reinterpret_cast<const f32x4*>(p0 + (size_t)p * NN * HID);

    const f32x4 w4 = *reinterpret_cast<const f32x4*>(&W3[HID + (lane << 2)]);
    const f32x4 u4 = *reinterpret_cast<const f32x4*>(&c[(lane << 2)]);
    const f32x4 v4 = *reinterpret_cast<const f32x4*>(&c[HID + (lane << 2)]);
    const f32x4 zs4 = s * w4;

    union { ushort u[4]; u32x2 v; } pz, ps;
    pz.u[0] = f2b(s.x);   pz.u[1] = f2b(s.y);
    pz.u[2] = f2b(s.z);   pz.u[3] = f2b(s.w);
    ps.u[0] = f2b(zs4.x); ps.u[1] = f2b(zs4.y);
    ps.u[2] = f2b(zs4.z); ps.u[3] = f2b(zs4.w);
    *reinterpret_cast<u32x2*>(&zb [(size_t)node * HID + (lane << 2)]) = pz.v;
    *reinterpret_cast<u32x2*>(&zsb[(size_t)node * HID + (lane << 2)]) = ps.v;

    const float r0 = fmaxf(s.x, 0.f), r1 = fmaxf(s.y, 0.f);
    const float r2 = fmaxf(s.z, 0.f), r3 = fmaxf(s.w, 0.f);
    float pa = r0 * u4.x + r1 * u4.y + r2 * u4.z + r3 * u4.w;
    float pb = r0 * v4.x + r1 * v4.y + r2 * v4.z + r3 * v4.w;

    #pragma unroll
    for (int off = 32; off; off >>= 1) {
        pa += __shfl_down(pa, off);
        pb += __shfl_down(pb, off);
    }
    if (lane == 0) { av[node] = pa; bv[node] = pb; }
}

// ---------------------------------------------------------------------------
// 2 edges per wave (32 lanes each): out = sigmoid(a[i]+b[j]+dot(zs[i],z[j]))
__global__ __launch_bounds__(256) void k_edge(
    const int* __restrict__ e1, const int* __restrict__ e2,
    const ushort* __restrict__ zb, const ushort* __restrict__ zsb,
    const float* __restrict__ av, const float* __restrict__ bv,
    float* __restrict__ out)
{
    const long long wid = (((long long)blockIdx.x * blockDim.x) + threadIdx.x) >> 6;
    const int lane = threadIdx.x & 63;
    const int half = lane >> 5;
    const int l32  = lane & 31;
    const long long e = 2LL * wid + half;
    if (e >= 2LL * NE) return;

    const int* ep = (e < NE) ? &e1[2 * (int)e] : &e2[2 * ((int)e - NE)];
    const int i = ep[0];
    const int j = ep[1];

    const bf16x8 zi = *reinterpret_cast<const bf16x8*>(&zsb[(size_t)i * HID + (l32 << 3)]);
    const bf16x8 zj = *reinterpret_cast<const bf16x8*>(&zb [(size_t)j * HID + (l32 << 3)]);
    float p = 0.f;
    #pragma unroll
    for (int t = 0; t < 8; ++t)
        p = fmaf(b2f((ushort)zi[t]), b2f((ushort)zj[t]), p);

    #pragma unroll
    for (int m = 16; m; m >>= 1)
        p += __shfl_xor(p, m);

    if (l32 == 0) {
        const float logit = av[i] + bv[j] + p;
        out[e] = 1.f / (1.f + expf(-logit));
    }
}

// ---------------------------------------------------------------------------
extern "C" void kernel_launch(void* const* d_in, const int* in_sizes, int n_in,
                              void* d_out, int out_size, void* d_ws, size_t ws_size,
                              hipStream_t stream)
{
    const float* X   = (const float*)d_in[0];
    const float* adj = (const float*)d_in[1];
    const int*   e1  = (const int*)d_in[2];
    const int*   e2  = (const int*)d_in[3];
    const float* W   = (const float*)d_in[4];
    const float* W2  = (const float*)d_in[5];
    const float* W3  = (const float*)d_in[6];
    float* out = (float*)d_out;

    float*  ws     = (float*)d_ws;
    float*  a      = ws;                                   // NN
    float*  b      = a + NN;                               // NN
    float*  c      = b + NN;                               // 512
    ushort* Wt2    = (ushort*)(c + 512);                   // 16 panels * 8192
    ushort* XWt2   = Wt2  + (size_t)16 * 8192;             // 320 panels * 8192
    ushort* zb     = XWt2 + (size_t)320 * 8192;            // NN*HID
    ushort* zsb    = zb   + (size_t)NN * HID;              // NN*HID
    float*  XWpart = (float*)(zsb + (size_t)NN * HID);     // SKX*NN*HID
    float*  Cpart  = XWpart + (size_t)SKX * NN * HID;      // SKA*NN*HID

    const dim3 blk(256);

    // W -> tiled bf16 panels (K=512 -> 16 panels)
    cvt_tiled<<<dim3(16), blk, 0, stream>>>(W, Wt2, IND, 1, 0);

    // XWpart = X @ W  (split-K = 4, direct store)
    gemm_bt<<<dim3(79, SKX), dim3(512), 0, stream>>>(
        X, Wt2, XWpart, NN, IND, IND, KCHX, (size_t)NN * HID);

    // sum partials -> tiled bf16 panels (KPAD=10240 -> 320 panels, zero-padded)
    cvt_tiled<<<dim3(KPAD / 32), blk, 0, stream>>>(
        XWpart, XWt2, NN, SKX, (size_t)NN * HID);

    // Cpart = adj @ XW  (split-K = 8, direct store)
    gemm_bt<<<dim3(79, SKA), dim3(512), 0, stream>>>(
        adj, XWt2, Cpart, NN, NN, NN, KCHA, (size_t)NN * HID);

    // c = [u; v]
    k_uv<<<dim3(2), blk, 0, stream>>>(W2, W3, c);

    // reduce partials + per-node tables
    k_node<<<dim3((NN * 64) / 256), blk, 0, stream>>>(Cpart, c, W3, zb, zsb, a, b);

    // per-edge output (2 edges / wave)
    k_edge<<<dim3((NE * 64) / 256), blk, 0, stream>>>(e1, e2, zb, zsb, a, b, out);
}

// Round 10
// 278.854 us; speedup vs baseline: 1.4299x; 1.0895x over previous
//
#include <hip/hip_runtime.h>
#include <hip/hip_bf16.h>
#include <math.h>

#define NN   10000
#define IND  512
#define HID  256
#define NE   400000
#define KPAD 10240   // adj GEMM K padded (320 panels of 32)
#define SKA  8       // adj split-K: k_chunk 1280, nt 40
#define KCHA 1280
#define BM   128

typedef __attribute__((ext_vector_type(4))) float  f32x4;
typedef __attribute__((ext_vector_type(4))) int    i32x4;
typedef __attribute__((ext_vector_type(2))) uint   u32x2;
typedef __attribute__((ext_vector_type(8))) short  bf16x8;

static __device__ inline ushort f2b(float f) {
    union { __hip_bfloat16 b; ushort u; } c;
    c.b = __float2bfloat16(f);
    return c.u;
}
static __device__ inline float b2f(ushort u) {
    union { uint t; float f; } c;
    c.t = (uint)u << 16;
    return c.f;
}
static __device__ inline void gload_lds16(const void* g, void* l) {
    __builtin_amdgcn_global_load_lds(
        (const __attribute__((address_space(1))) unsigned int*)g,
        (__attribute__((address_space(3))) unsigned int*)l, 16, 0, 0);
}
// pinned-order A prefetch: exactly 2 vmem loads (vmcnt accounting)
static __device__ inline void aload(const float* p, f32x4& a, f32x4& b) {
    asm volatile("global_load_dwordx4 %0, %2, off\n\t"
                 "global_load_dwordx4 %1, %2, off offset:16"
                 : "=&v"(a), "=&v"(b) : "v"(p) : "memory");
}

// ---------------------------------------------------------------------------
// W -> K-step panels (16 KB each), panel linear order == GEMM LDS frag order:
//   slot s (16 B): g = s>>6, l = s&63 -> B[col = g*16 + (l&15)][k8 = l>>4]
__global__ __launch_bounds__(256) void cvt_tiled(
    const float* __restrict__ src, ushort* __restrict__ dst, int R)
{
    __shared__ float t[32][256];
    const int p   = blockIdx.x;
    const int tid = threadIdx.x;
    const int r0  = p << 5;

    #pragma unroll
    for (int j = 0; j < 8; ++j) {
        const int f   = (j << 8) + tid;
        const int row = f >> 6;
        const int c4  = (f & 63) << 2;
        f32x4 v = {0.f, 0.f, 0.f, 0.f};
        if (r0 + row < R)
            v = *reinterpret_cast<const f32x4*>(&src[(size_t)(r0 + row) * 256 + c4]);
        *reinterpret_cast<f32x4*>(&t[row][c4]) = v;
    }
    __syncthreads();

    #pragma unroll
    for (int qq = 0; qq < 4; ++qq) {
        const int s   = (qq << 8) + tid;
        const int g   = s >> 6, l = s & 63;
        const int col = (g << 4) + (l & 15);
        const int k8  = (l >> 4) << 3;
        union { ushort u[8]; i32x4 v4; } pk;
        #pragma unroll
        for (int i = 0; i < 8; ++i) pk.u[i] = f2b(t[k8 + i][col]);
        *reinterpret_cast<i32x4*>(&dst[((size_t)p << 13) + ((size_t)s << 3)]) = pk.v4;
    }
}

// zero pad panels 316..319 of the XW panel array
__global__ __launch_bounds__(256) void zero_tail(ushort* __restrict__ dst)
{
    const int tid = blockIdx.x * 256 + threadIdx.x;   // 1024 threads
    const i32x4 z = {0, 0, 0, 0};
    ushort* base = dst + ((size_t)316 << 13);
    #pragma unroll
    for (int i = 0; i < 4; ++i)
        *reinterpret_cast<i32x4*>(&base[(size_t)((tid << 2) + i) << 3]) = z;
}

// ---------------------------------------------------------------------------
// PANEL=false: Cpart[sk][M,256] f32 = A[M, chunk] @ B(chunk), direct store.
// PANEL=true : Cout = bf16 K-step panels of (A @ B) (fused cvt_tiled), sk==0.
// A f32 (cvt bf16 on the fly, reg->LDS), B pre-tiled bf16 panels staged via
// contiguous 1 KB global_load_lds. 128x256 block, 8 waves (2x4), wave tile
// 64x64, BK=32, LDS dbuf, depth-2 A prefetch, counted vmcnt (never drains
// mid-loop; drained + reg-liveness-pinned before the epilogue).
template<bool PANEL>
__global__ __launch_bounds__(512, 4) void gemm_bt(
    const float* __restrict__ A, const ushort* __restrict__ BT2,
    void* __restrict__ Cout, int M, int K_real, int lda, int k_chunk,
    size_t c_stride)
{
    __shared__ ushort Alds[2][4096];   // 16 KB
    __shared__ ushort Blds[2][8192];   // 32 KB

    const int tid  = threadIdx.x;      // 0..511
    const int lane = tid & 63;
    const int w    = tid >> 6;         // wave 0..7
    const int wm   = w >> 2;           // row half
    const int wn   = w & 3;            // col quadrant

    // bijective XCD-chunk swizzle; row fastest, sk-major
    const int gx  = gridDim.x;
    const int nwg = gx * gridDim.y;
    const int lin = blockIdx.y * gx + blockIdx.x;
    const int q = nwg >> 3, r = nwg & 7;
    const int xc = lin & 7, o = lin >> 3;
    const int work = (xc < r ? xc * (q + 1) : r * (q + 1) + (xc - r) * q) + o;
    const int row0 = (work % gx) * BM;
    const int sk   = work / gx;
    const int kbeg = sk * k_chunk;

    // A staging: thread t -> (row t>>2, kgroup t&3); LDS slot = inverse frag map
    const int arow = tid >> 2;
    const int akg  = tid & 3;
    const int grow = row0 + arow;
    const bool aok = grow < M;
    const bool lastrow = (grow == M - 1);
    const float* aptr = A + (size_t)grow * lda + kbeg + (akg << 3);
    const int aslot = ((arow >> 4) << 6) | (akg << 4) | (arow & 15);

    const int nt = k_chunk >> 5;

    f32x4 acc[4][4];
    #pragma unroll
    for (int i = 0; i < 4; ++i)
        #pragma unroll
        for (int j = 0; j < 4; ++j)
            acc[i][j] = (f32x4){0.f, 0.f, 0.f, 0.f};

    auto apick = [&](int kn) -> const float* {
        const bool ok = aok && (kn < k_chunk) &&
                        (!lastrow || (kbeg + kn + (akg << 3) + 8) <= K_real);
        return ok ? (aptr + kn) : A;
    };
    auto stageB = [&](int t, int buf) {
        const ushort* ps = BT2 + (((size_t)(kbeg >> 5) + t) << 13) + ((w << 1) << 9);
        gload_lds16(ps,       &Blds[buf][(w << 1) << 9]);
        gload_lds16(ps + 512, &Blds[buf][((w << 1) + 1) << 9]);
    };
    auto writeA = [&](int buf, const f32x4& x0, const f32x4& x1) {
        union { ushort u[8]; i32x4 v4; } pk;
        pk.u[0]=f2b(x0.x); pk.u[1]=f2b(x0.y); pk.u[2]=f2b(x0.z); pk.u[3]=f2b(x0.w);
        pk.u[4]=f2b(x1.x); pk.u[5]=f2b(x1.y); pk.u[6]=f2b(x1.z); pk.u[7]=f2b(x1.w);
        *reinterpret_cast<i32x4*>(&Alds[buf][aslot << 3]) = pk.v4;
    };
    auto compute = [&](int buf) {
        bf16x8 bfr[4];
        #pragma unroll
        for (int nf = 0; nf < 4; ++nf)
            bfr[nf] = *reinterpret_cast<const bf16x8*>(
                &Blds[buf][((((wn << 2) + nf) << 6) | lane) << 3]);
        #pragma unroll
        for (int mf = 0; mf < 4; ++mf) {
            const bf16x8 af = *reinterpret_cast<const bf16x8*>(
                &Alds[buf][((((wm << 2) + mf) << 6) | lane) << 3]);
            #pragma unroll
            for (int nf = 0; nf < 4; ++nf)
                acc[mf][nf] = __builtin_amdgcn_mfma_f32_16x16x32_bf16(
                    af, bfr[nf], acc[mf][nf], 0, 0, 0);
        }
    };

    f32x4 aP0, aP1, aQ0, aQ1;
    // one steady step: consume A(t+1) (cons), issue B(t+1) + A(t+2) (next)
    auto STEP = [&](int t, f32x4& c0, f32x4& c1, f32x4& n0, f32x4& n1) {
        stageB(t + 1, (t + 1) & 1);
        aload(apick((t + 2) << 5), n0, n1);
        compute(t & 1);
        asm volatile("s_waitcnt vmcnt(4)" ::: "memory");   // A(t+1) landed
        __builtin_amdgcn_sched_barrier(0);
        writeA((t + 1) & 1, c0, c1);
        asm volatile("s_waitcnt vmcnt(2) lgkmcnt(0)" ::: "memory"); // B(t+1) in LDS
        __builtin_amdgcn_sched_barrier(0);
        __builtin_amdgcn_s_barrier();
    };

    // ---- prologue: A0 -> LDS, A1 in flight ----
    aload(apick(0), aP0, aP1);
    stageB(0, 0);
    aload(apick(32), aQ0, aQ1);
    asm volatile("s_waitcnt vmcnt(4)" ::: "memory");       // A0 landed
    __builtin_amdgcn_sched_barrier(0);
    writeA(0, aP0, aP1);
    asm volatile("s_waitcnt vmcnt(2) lgkmcnt(0)" ::: "memory"); // B0 in LDS
    __builtin_amdgcn_sched_barrier(0);
    __builtin_amdgcn_s_barrier();

    // ---- main loop (manual 2-unroll, static reg parity) ----
    int t = 0;
    for (; t + 1 < nt - 1; t += 2) {
        STEP(t,     aQ0, aQ1, aP0, aP1);
        STEP(t + 1, aP0, aP1, aQ0, aQ1);
    }
    if (t < nt - 1) STEP(t, aQ0, aQ1, aP0, aP1);
    compute((nt - 1) & 1);

    // ---- FIX: drain the dangling junk A-prefetch before the epilogue and
    // pin aP/aQ live across the wait, so the register allocator cannot
    // reuse their VGPRs while the loads' writeback is still pending.
    asm volatile("s_waitcnt vmcnt(0)" ::: "memory");
    __builtin_amdgcn_sched_barrier(0);
    asm volatile("" :: "v"(aP0), "v"(aP1), "v"(aQ0), "v"(aQ1));

    if constexpr (!PANEL) {
        // f32 partial store; col = lane&15, row = (lane>>4)*4 + rr
        float* C = (float*)Cout + (size_t)sk * c_stride;
        #pragma unroll
        for (int mf = 0; mf < 4; ++mf) {
            const int rbase = row0 + (wm << 6) + mf * 16 + ((lane >> 4) << 2);
            #pragma unroll
            for (int nf = 0; nf < 4; ++nf) {
                const int col = (wn << 6) + nf * 16 + (lane & 15);
                #pragma unroll
                for (int rr = 0; rr < 4; ++rr) {
                    const int row = rbase + rr;
                    if (row < M) C[(size_t)row * HID + col] = acc[mf][nf][rr];
                }
            }
        }
    } else {
        // bf16 panel store via LDS re-layout; block covers panels (row0>>5)+0..3
        ushort* Cp = (ushort*)Cout;
        ushort* Lp = Blds[((nt - 1) & 1) ^ 1];     // free buffer
        #pragma unroll
        for (int pp = 0; pp < 4; ++pp) {
            if ((w >> 2) == (pp >> 1)) {
                #pragma unroll
                for (int mfh = 0; mfh < 2; ++mfh) {
                    const int mf = ((pp & 1) << 1) + mfh;
                    const int kb = (mfh << 4) + ((lane >> 4) << 2);  // 0..28
                    #pragma unroll
                    for (int nf = 0; nf < 4; ++nf) {
                        const int col = (wn << 6) + (nf << 4) + (lane & 15);
                        const int s = ((col >> 4) << 6) | ((kb >> 3) << 4) | (col & 15);
                        union { ushort u[4]; u32x2 v; } pk;
                        #pragma unroll
                        for (int rr = 0; rr < 4; ++rr) {
                            const int row = row0 + (pp << 5) + kb + rr;
                            pk.u[rr] = (row < M) ? f2b(acc[mf][nf][rr]) : (ushort)0;
                        }
                        *reinterpret_cast<u32x2*>(&Lp[(s << 3) + (kb & 7)]) = pk.v;
                    }
                }
            }
            __syncthreads();
            const size_t P = (size_t)((row0 >> 5) + pp);
            const ushort* sp = &Lp[tid << 4];
            ushort* gp = Cp + (P << 13) + ((size_t)tid << 4);
            *reinterpret_cast<i32x4*>(gp)     = *reinterpret_cast<const i32x4*>(sp);
            *reinterpret_cast<i32x4*>(gp + 8) = *reinterpret_cast<const i32x4*>(sp + 8);
            __syncthreads();
        }
    }
}

// ---------------------------------------------------------------------------
__global__ void k_uv(const float* __restrict__ W2, const float* __restrict__ W3,
                     float* __restrict__ c)
{
    const int j = blockIdx.x * blockDim.x + threadIdx.x;
    if (j >= 2 * HID) return;
    float s = 0.f;
    for (int m = 0; m < HID; ++m)
        s = fmaf(W2[(size_t)j * HID + m], W3[m], s);
    c[j] = s;
}

// ---------------------------------------------------------------------------
// Reduce SKA partials -> z; write bf16 z table; a = relu(z)·u, b = relu(z)·v
__global__ __launch_bounds__(256) void k_node(
    const float* __restrict__ Cpart, const float* __restrict__ c,
    ushort* __restrict__ zb, float* __restrict__ av, float* __restrict__ bv)
{
    const int node = (int)((blockIdx.x * blockDim.x + threadIdx.x) >> 6);
    const int lane = threadIdx.x & 63;
    if (node >= NN) return;

    const float* p0 = Cpart + (size_t)node * HID + (lane << 2);
    f32x4 s = *reinterpret_cast<const f32x4*>(p0);
    #pragma unroll
    for (int p = 1; p < SKA; ++p)
        s += *reinterpret_cast<const f32x4*>(p0 + (size_t)p * NN * HID);

    const f32x4 u4 = *reinterpret_cast<const f32x4*>(&c[(lane << 2)]);
    const f32x4 v4 = *reinterpret_cast<const f32x4*>(&c[HID + (lane << 2)]);

    union { ushort u[4]; u32x2 v; } pz;
    pz.u[0] = f2b(s.x); pz.u[1] = f2b(s.y);
    pz.u[2] = f2b(s.z); pz.u[3] = f2b(s.w);
    *reinterpret_cast<u32x2*>(&zb[(size_t)node * HID + (lane << 2)]) = pz.v;

    const float r0 = fmaxf(s.x, 0.f), r1 = fmaxf(s.y, 0.f);
    const float r2 = fmaxf(s.z, 0.f), r3 = fmaxf(s.w, 0.f);
    float pa = r0 * u4.x + r1 * u4.y + r2 * u4.z + r3 * u4.w;
    float pb = r0 * v4.x + r1 * v4.y + r2 * v4.z + r3 * v4.w;

    #pragma unroll
    for (int off = 32; off; off >>= 1) {
        pa += __shfl_down(pa, off);
        pb += __shfl_down(pb, off);
    }
    if (lane == 0) { av[node] = pa; bv[node] = pb; }
}

// ---------------------------------------------------------------------------
// 4 edges per wave (16 lanes each): out = sigmoid(a[i]+b[j]+sum z_i z_j w3b)
__global__ __launch_bounds__(256) void k_edge(
    const int* __restrict__ e1, const int* __restrict__ e2,
    const ushort* __restrict__ zb, const float* __restrict__ av,
    const float* __restrict__ bv, const float* __restrict__ W3,
    float* __restrict__ out)
{
    const long long wid = (((long long)blockIdx.x * blockDim.x) + threadIdx.x) >> 6;
    const int lane = threadIdx.x & 63;
    const int s16  = lane & 15;
    const long long e = 4LL * wid + (lane >> 4);
    if (e >= 2LL * NE) return;

    // per-lane w3b slice (16 f32, held in VGPRs)
    const float* w3p = W3 + HID + (s16 << 4);
    f32x4 wv[4];
    #pragma unroll
    for (int i = 0; i < 4; ++i)
        wv[i] = *reinterpret_cast<const f32x4*>(w3p + (i << 2));

    const int* ep = (e < NE) ? &e1[2 * (int)e] : &e2[2 * ((int)e - NE)];
    const int i = ep[0];
    const int j = ep[1];

    const ushort* zi = &zb[(size_t)i * HID + (s16 << 4)];
    const ushort* zj = &zb[(size_t)j * HID + (s16 << 4)];
    const bf16x8 zi0 = *reinterpret_cast<const bf16x8*>(zi);
    const bf16x8 zi1 = *reinterpret_cast<const bf16x8*>(zi + 8);
    const bf16x8 zj0 = *reinterpret_cast<const bf16x8*>(zj);
    const bf16x8 zj1 = *reinterpret_cast<const bf16x8*>(zj + 8);

    float p = 0.f;
    #pragma unroll
    for (int tt = 0; tt < 8; ++tt)
        p = fmaf(b2f((ushort)zi0[tt]) * b2f((ushort)zj0[tt]), wv[tt >> 2][tt & 3], p);
    #pragma unroll
    for (int tt = 0; tt < 8; ++tt)
        p = fmaf(b2f((ushort)zi1[tt]) * b2f((ushort)zj1[tt]), wv[2 + (tt >> 2)][tt & 3], p);

    #pragma unroll
    for (int m = 8; m; m >>= 1)
        p += __shfl_xor(p, m);

    if (s16 == 0) {
        const float logit = av[i] + bv[j] + p;
        out[e] = 1.f / (1.f + expf(-logit));
    }
}

// ---------------------------------------------------------------------------
extern "C" void kernel_launch(void* const* d_in, const int* in_sizes, int n_in,
                              void* d_out, int out_size, void* d_ws, size_t ws_size,
                              hipStream_t stream)
{
    const float* X   = (const float*)d_in[0];
    const float* adj = (const float*)d_in[1];
    const int*   e1  = (const int*)d_in[2];
    const int*   e2  = (const int*)d_in[3];
    const float* W   = (const float*)d_in[4];
    const float* W2  = (const float*)d_in[5];
    const float* W3  = (const float*)d_in[6];
    float* out = (float*)d_out;

    float*  ws    = (float*)d_ws;
    float*  a     = ws;                                  // NN
    float*  b     = a + NN;                              // NN
    float*  c     = b + NN;                              // 512
    ushort* Wt2   = (ushort*)(c + 512);                  // 16 panels * 8192
    ushort* XWt2  = Wt2  + (size_t)16 * 8192;            // 320 panels * 8192
    ushort* zb    = XWt2 + (size_t)320 * 8192;           // NN*HID
    float*  Cpart = (float*)(zb + (size_t)NN * HID);     // SKA*NN*HID

    const dim3 blk(256);

    // W -> tiled bf16 panels (K=512 -> 16 panels)
    cvt_tiled<<<dim3(16), blk, 0, stream>>>(W, Wt2, IND);

    // zero pad panels 316..319 of XWt2
    zero_tail<<<dim3(4), blk, 0, stream>>>(XWt2);

    // XW panels = X @ W, fused panel epilogue (no split-K, no f32 round-trip)
    gemm_bt<true><<<dim3(79, 1), dim3(512), 0, stream>>>(
        X, Wt2, XWt2, NN, IND, IND, IND, 0);

    // Cpart = adj @ XW  (split-K = 8, direct f32 store)
    gemm_bt<false><<<dim3(79, SKA), dim3(512), 0, stream>>>(
        adj, XWt2, Cpart, NN, NN, NN, KCHA, (size_t)NN * HID);

    // c = [u; v]
    k_uv<<<dim3(2), blk, 0, stream>>>(W2, W3, c);

    // reduce partials + z table + a,b
    k_node<<<dim3((NN * 64) / 256), blk, 0, stream>>>(Cpart, c, zb, a, b);

    // per-edge output (4 edges / wave)
    k_edge<<<dim3((2 * NE * 16) / 256), blk, 0, stream>>>(e1, e2, zb, a, b, W3, out);
}

// Round 11
// 263.897 us; speedup vs baseline: 1.5109x; 1.0567x over previous
//
#include <hip/hip_runtime.h>
#include <hip/hip_bf16.h>
#include <math.h>

#define NN   10000
#define IND  512
#define HID  256
#define NE   400000
#define KPAD 10240   // adj GEMM K padded (320 panels of 32)
#define SKA  8       // adj split-K: k_chunk 1280, nt 40
#define KCHA 1280
#define BM   128

typedef __attribute__((ext_vector_type(4))) float  f32x4;
typedef __attribute__((ext_vector_type(4))) int    i32x4;
typedef __attribute__((ext_vector_type(2))) uint   u32x2;
typedef __attribute__((ext_vector_type(8))) short  bf16x8;

static __device__ inline ushort f2b(float f) {
    union { __hip_bfloat16 b; ushort u; } c;
    c.b = __float2bfloat16(f);
    return c.u;
}
static __device__ inline float b2f(ushort u) {
    union { uint t; float f; } c;
    c.t = (uint)u << 16;
    return c.f;
}
static __device__ inline void gload_lds16(const void* g, void* l) {
    __builtin_amdgcn_global_load_lds(
        (const __attribute__((address_space(1))) unsigned int*)g,
        (__attribute__((address_space(3))) unsigned int*)l, 16, 0, 0);
}
// pinned-order A prefetch: exactly 2 vmem loads (vmcnt accounting)
static __device__ inline void aload(const float* p, f32x4& a, f32x4& b) {
    asm volatile("global_load_dwordx4 %0, %2, off\n\t"
                 "global_load_dwordx4 %1, %2, off offset:16"
                 : "=&v"(a), "=&v"(b) : "v"(p) : "memory");
}

// ---------------------------------------------------------------------------
// W -> K-step panels (16 KB each), panel linear order == GEMM LDS frag order:
//   slot s (16 B): g = s>>6, l = s&63 -> B[col = g*16 + (l&15)][k8 = l>>4]
__global__ __launch_bounds__(256) void cvt_tiled(
    const float* __restrict__ src, ushort* __restrict__ dst, int R)
{
    __shared__ float t[32][256];
    const int p   = blockIdx.x;
    const int tid = threadIdx.x;
    const int r0  = p << 5;

    #pragma unroll
    for (int j = 0; j < 8; ++j) {
        const int f   = (j << 8) + tid;
        const int row = f >> 6;
        const int c4  = (f & 63) << 2;
        f32x4 v = {0.f, 0.f, 0.f, 0.f};
        if (r0 + row < R)
            v = *reinterpret_cast<const f32x4*>(&src[(size_t)(r0 + row) * 256 + c4]);
        *reinterpret_cast<f32x4*>(&t[row][c4]) = v;
    }
    __syncthreads();

    #pragma unroll
    for (int qq = 0; qq < 4; ++qq) {
        const int s   = (qq << 8) + tid;
        const int g   = s >> 6, l = s & 63;
        const int col = (g << 4) + (l & 15);
        const int k8  = (l >> 4) << 3;
        union { ushort u[8]; i32x4 v4; } pk;
        #pragma unroll
        for (int i = 0; i < 8; ++i) pk.u[i] = f2b(t[k8 + i][col]);
        *reinterpret_cast<i32x4*>(&dst[((size_t)p << 13) + ((size_t)s << 3)]) = pk.v4;
    }
}

// zero pad panels 316..319 of the XW panel array
__global__ __launch_bounds__(256) void zero_tail(ushort* __restrict__ dst)
{
    const int tid = blockIdx.x * 256 + threadIdx.x;   // 1024 threads
    const i32x4 z = {0, 0, 0, 0};
    ushort* base = dst + ((size_t)316 << 13);
    #pragma unroll
    for (int i = 0; i < 4; ++i)
        *reinterpret_cast<i32x4*>(&base[(size_t)((tid << 2) + i) << 3]) = z;
}

// ---------------------------------------------------------------------------
// PANEL=false: Cpart[sk][M,256] bf16 = A[M, chunk] @ B(chunk), direct store.
// PANEL=true : Cout = bf16 K-step panels of (A @ B) (fused cvt_tiled), sk==0.
// A f32 (cvt bf16 on the fly, reg->LDS dbuf), B pre-tiled bf16 panels staged
// 2 steps ahead into a ring-3 LDS buffer via contiguous 1 KB global_load_lds.
// 128x256 block, 8 waves (2x4), wave tile 64x64, BK=32. Per step exactly one
// "s_waitcnt vmcnt(4)" (drains B(t+1)+A(t+1), both issued a full step earlier)
// + lgkmcnt(0) + barrier. No mid-loop drain; tail drains vmcnt(0).
template<bool PANEL>
__global__ __launch_bounds__(512, 4) void gemm_bt(
    const float* __restrict__ A, const ushort* __restrict__ BT2,
    void* __restrict__ Cout, int M, int K_real, int lda, int k_chunk,
    size_t c_stride)
{
    __shared__ ushort Alds[2][4096];   // 16 KB (A dbuf)
    __shared__ ushort Blds[3][8192];   // 48 KB (B ring-3)

    const int tid  = threadIdx.x;      // 0..511
    const int lane = tid & 63;
    const int w    = tid >> 6;         // wave 0..7
    const int wm   = w >> 2;           // row half
    const int wn   = w & 3;            // col quadrant

    // bijective XCD-chunk swizzle; row fastest, sk-major
    const int gx  = gridDim.x;
    const int nwg = gx * gridDim.y;
    const int lin = blockIdx.y * gx + blockIdx.x;
    const int q = nwg >> 3, r = nwg & 7;
    const int xc = lin & 7, o = lin >> 3;
    const int work = (xc < r ? xc * (q + 1) : r * (q + 1) + (xc - r) * q) + o;
    const int row0 = (work % gx) * BM;
    const int sk   = work / gx;
    const int kbeg = sk * k_chunk;

    // A staging: thread t -> (row t>>2, kgroup t&3); LDS slot = inverse frag map
    const int arow = tid >> 2;
    const int akg  = tid & 3;
    const int grow = row0 + arow;
    const bool aok = grow < M;
    const bool lastrow = (grow == M - 1);
    const float* aptr = A + (size_t)grow * lda + kbeg + (akg << 3);
    const int aslot = ((arow >> 4) << 6) | (akg << 4) | (arow & 15);

    const int nt = k_chunk >> 5;       // 40 or 16 (even, >= 3)

    f32x4 acc[4][4];
    #pragma unroll
    for (int i = 0; i < 4; ++i)
        #pragma unroll
        for (int j = 0; j < 4; ++j)
            acc[i][j] = (f32x4){0.f, 0.f, 0.f, 0.f};

    auto apick = [&](int kn) -> const float* {
        const bool ok = aok && (kn < k_chunk) &&
                        (!lastrow || (kbeg + kn + (akg << 3) + 8) <= K_real);
        return ok ? (aptr + kn) : A;
    };
    // stage B panel tile tt into ring slot tt%3: 2 contiguous 1 KB gloads/wave
    auto stageB = [&](int tt) {
        const int slot = tt % 3;
        const ushort* ps = BT2 + (((size_t)(kbeg >> 5) + tt) << 13) + ((w << 1) << 9);
        gload_lds16(ps,       &Blds[slot][(w << 1) << 9]);
        gload_lds16(ps + 512, &Blds[slot][((w << 1) + 1) << 9]);
    };
    auto writeA = [&](int buf, const f32x4& x0, const f32x4& x1) {
        union { ushort u[8]; i32x4 v4; } pk;
        pk.u[0]=f2b(x0.x); pk.u[1]=f2b(x0.y); pk.u[2]=f2b(x0.z); pk.u[3]=f2b(x0.w);
        pk.u[4]=f2b(x1.x); pk.u[5]=f2b(x1.y); pk.u[6]=f2b(x1.z); pk.u[7]=f2b(x1.w);
        *reinterpret_cast<i32x4*>(&Alds[buf][aslot << 3]) = pk.v4;
    };
    auto compute = [&](int tt) {
        const ushort* Bb = Blds[tt % 3];
        const ushort* Ab = Alds[tt & 1];
        bf16x8 bfr[4];
        #pragma unroll
        for (int nf = 0; nf < 4; ++nf)
            bfr[nf] = *reinterpret_cast<const bf16x8*>(
                &Bb[((((wn << 2) + nf) << 6) | lane) << 3]);
        #pragma unroll
        for (int mf = 0; mf < 4; ++mf) {
            const bf16x8 af = *reinterpret_cast<const bf16x8*>(
                &Ab[((((wm << 2) + mf) << 6) | lane) << 3]);
            #pragma unroll
            for (int nf = 0; nf < 4; ++nf)
                acc[mf][nf] = __builtin_amdgcn_mfma_f32_16x16x32_bf16(
                    af, bfr[nf], acc[mf][nf], 0, 0, 0);
        }
    };

    f32x4 aP0, aP1, aQ0, aQ1;
    // steady step t: stage B(t+2), load A(t+2); compute(t); end-wait drains
    // B(t+1)+A(t+1) (issued in step t-1; queue order B-then-A => vmcnt(4)).
    auto STEP = [&](int t, f32x4& c0, f32x4& c1, f32x4& n0, f32x4& n1) {
        stageB(t + 2);
        aload(apick((t + 2) << 5), n0, n1);
        compute(t);
        asm volatile("s_waitcnt vmcnt(4)" ::: "memory");
        __builtin_amdgcn_sched_barrier(0);
        writeA((t + 1) & 1, c0, c1);
        asm volatile("s_waitcnt lgkmcnt(0)" ::: "memory");
        __builtin_amdgcn_s_barrier();
    };

    // ---- prologue: queue = [B0, B1, A0, A1]; drain B0,B1,A0 ----
    stageB(0);
    stageB(1);
    aload(apick(0),  aP0, aP1);
    aload(apick(32), aQ0, aQ1);
    asm volatile("s_waitcnt vmcnt(2)" ::: "memory");
    __builtin_amdgcn_sched_barrier(0);
    writeA(0, aP0, aP1);
    asm volatile("s_waitcnt lgkmcnt(0)" ::: "memory");
    __builtin_amdgcn_s_barrier();

    // ---- main: steps t = 0 .. nt-3 (manual 2-unroll, static reg parity) ----
    int t = 0;
    for (; t + 1 < nt - 2; t += 2) {
        STEP(t,     aQ0, aQ1, aP0, aP1);
        STEP(t + 1, aP0, aP1, aQ0, aQ1);
    }
    bool lastInP = false;
    if (t < nt - 2) { STEP(t, aQ0, aQ1, aP0, aP1); lastInP = true; }

    // ---- tail: tiles nt-2 and nt-1 (everything already in flight) ----
    compute(nt - 2);
    asm volatile("s_waitcnt vmcnt(0)" ::: "memory");   // B(nt-1), A(nt-1) landed
    __builtin_amdgcn_sched_barrier(0);
    if (lastInP) writeA((nt - 1) & 1, aP0, aP1);
    else         writeA((nt - 1) & 1, aQ0, aQ1);
    asm volatile("s_waitcnt lgkmcnt(0)" ::: "memory");
    __builtin_amdgcn_s_barrier();
    compute(nt - 1);

    if constexpr (!PANEL) {
        // bf16 partial store; col = lane&15, row = (lane>>4)*4 + rr
        ushort* C = (ushort*)Cout + (size_t)sk * c_stride;
        #pragma unroll
        for (int mf = 0; mf < 4; ++mf) {
            const int rbase = row0 + (wm << 6) + mf * 16 + ((lane >> 4) << 2);
            #pragma unroll
            for (int nf = 0; nf < 4; ++nf) {
                const int col = (wn << 6) + nf * 16 + (lane & 15);
                #pragma unroll
                for (int rr = 0; rr < 4; ++rr) {
                    const int row = rbase + rr;
                    if (row < M) C[(size_t)row * HID + col] = f2b(acc[mf][nf][rr]);
                }
            }
        }
    } else {
        // bf16 panel store via LDS re-layout; block covers panels (row0>>5)+0..3
        // Lp = ring slot nt%3: last read at compute(nt-3), >=1 barrier ago.
        ushort* Cp = (ushort*)Cout;
        ushort* Lp = Blds[nt % 3];
        #pragma unroll
        for (int pp = 0; pp < 4; ++pp) {
            if ((w >> 2) == (pp >> 1)) {
                #pragma unroll
                for (int mfh = 0; mfh < 2; ++mfh) {
                    const int mf = ((pp & 1) << 1) + mfh;
                    const int kb = (mfh << 4) + ((lane >> 4) << 2);  // 0..28
                    #pragma unroll
                    for (int nf = 0; nf < 4; ++nf) {
                        const int col = (wn << 6) + (nf << 4) + (lane & 15);
                        const int s = ((col >> 4) << 6) | ((kb >> 3) << 4) | (col & 15);
                        union { ushort u[4]; u32x2 v; } pk;
                        #pragma unroll
                        for (int rr = 0; rr < 4; ++rr) {
                            const int row = row0 + (pp << 5) + kb + rr;
                            pk.u[rr] = (row < M) ? f2b(acc[mf][nf][rr]) : (ushort)0;
                        }
                        *reinterpret_cast<u32x2*>(&Lp[(s << 3) + (kb & 7)]) = pk.v;
                    }
                }
            }
            __syncthreads();
            const size_t P = (size_t)((row0 >> 5) + pp);
            const ushort* sp = &Lp[tid << 4];
            ushort* gp = Cp + (P << 13) + ((size_t)tid << 4);
            *reinterpret_cast<i32x4*>(gp)     = *reinterpret_cast<const i32x4*>(sp);
            *reinterpret_cast<i32x4*>(gp + 8) = *reinterpret_cast<const i32x4*>(sp + 8);
            __syncthreads();
        }
    }
}

// ---------------------------------------------------------------------------
__global__ void k_uv(const float* __restrict__ W2, const float* __restrict__ W3,
                     float* __restrict__ c)
{
    const int j = blockIdx.x * blockDim.x + threadIdx.x;
    if (j >= 2 * HID) return;
    float s = 0.f;
    for (int m = 0; m < HID; ++m)
        s = fmaf(W2[(size_t)j * HID + m], W3[m], s);
    c[j] = s;
}

// ---------------------------------------------------------------------------
// Reduce SKA bf16 partials -> z (f32); write bf16 z table; a,b scalars
__global__ __launch_bounds__(256) void k_node(
    const ushort* __restrict__ Cpart, const float* __restrict__ c,
    ushort* __restrict__ zb, float* __restrict__ av, float* __restrict__ bv)
{
    const int node = (int)((blockIdx.x * blockDim.x + threadIdx.x) >> 6);
    const int lane = threadIdx.x & 63;
    if (node >= NN) return;

    const ushort* p0 = Cpart + (size_t)node * HID + (lane << 2);
    f32x4 s = {0.f, 0.f, 0.f, 0.f};
    #pragma unroll
    for (int p = 0; p < SKA; ++p) {
        union { u32x2 v; ushort u[4]; } raw;
        raw.v = *reinterpret_cast<const u32x2*>(p0 + (size_t)p * NN * HID);
        s.x += b2f(raw.u[0]); s.y += b2f(raw.u[1]);
        s.z += b2f(raw.u[2]); s.w += b2f(raw.u[3]);
    }

    const f32x4 u4 = *reinterpret_cast<const f32x4*>(&c[(lane << 2)]);
    const f32x4 v4 = *reinterpret_cast<const f32x4*>(&c[HID + (lane << 2)]);

    union { ushort u[4]; u32x2 v; } pz;
    pz.u[0] = f2b(s.x); pz.u[1] = f2b(s.y);
    pz.u[2] = f2b(s.z); pz.u[3] = f2b(s.w);
    *reinterpret_cast<u32x2*>(&zb[(size_t)node * HID + (lane << 2)]) = pz.v;

    const float r0 = fmaxf(s.x, 0.f), r1 = fmaxf(s.y, 0.f);
    const float r2 = fmaxf(s.z, 0.f), r3 = fmaxf(s.w, 0.f);
    float pa = r0 * u4.x + r1 * u4.y + r2 * u4.z + r3 * u4.w;
    float pb = r0 * v4.x + r1 * v4.y + r2 * v4.z + r3 * v4.w;

    #pragma unroll
    for (int off = 32; off; off >>= 1) {
        pa += __shfl_down(pa, off);
        pb += __shfl_down(pb, off);
    }
    if (lane == 0) { av[node] = pa; bv[node] = pb; }
}

// ---------------------------------------------------------------------------
// 4 edges per wave (16 lanes each): out = sigmoid(a[i]+b[j]+sum z_i z_j w3b)
__global__ __launch_bounds__(256) void k_edge(
    const int* __restrict__ e1, const int* __restrict__ e2,
    const ushort* __restrict__ zb, const float* __restrict__ av,
    const float* __restrict__ bv, const float* __restrict__ W3,
    float* __restrict__ out)
{
    const long long wid = (((long long)blockIdx.x * blockDim.x) + threadIdx.x) >> 6;
    const int lane = threadIdx.x & 63;
    const int s16  = lane & 15;
    const long long e = 4LL * wid + (lane >> 4);
    if (e >= 2LL * NE) return;

    // per-lane w3b slice (16 f32, held in VGPRs)
    const float* w3p = W3 + HID + (s16 << 4);
    f32x4 wv[4];
    #pragma unroll
    for (int i = 0; i < 4; ++i)
        wv[i] = *reinterpret_cast<const f32x4*>(w3p + (i << 2));

    const int* ep = (e < NE) ? &e1[2 * (int)e] : &e2[2 * ((int)e - NE)];
    const int i = ep[0];
    const int j = ep[1];

    const ushort* zi = &zb[(size_t)i * HID + (s16 << 4)];
    const ushort* zj = &zb[(size_t)j * HID + (s16 << 4)];
    const bf16x8 zi0 = *reinterpret_cast<const bf16x8*>(zi);
    const bf16x8 zi1 = *reinterpret_cast<const bf16x8*>(zi + 8);
    const bf16x8 zj0 = *reinterpret_cast<const bf16x8*>(zj);
    const bf16x8 zj1 = *reinterpret_cast<const bf16x8*>(zj + 8);

    float p = 0.f;
    #pragma unroll
    for (int tt = 0; tt < 8; ++tt)
        p = fmaf(b2f((ushort)zi0[tt]) * b2f((ushort)zj0[tt]), wv[tt >> 2][tt & 3], p);
    #pragma unroll
    for (int tt = 0; tt < 8; ++tt)
        p = fmaf(b2f((ushort)zi1[tt]) * b2f((ushort)zj1[tt]), wv[2 + (tt >> 2)][tt & 3], p);

    #pragma unroll
    for (int m = 8; m; m >>= 1)
        p += __shfl_xor(p, m);

    if (s16 == 0) {
        const float logit = av[i] + bv[j] + p;
        out[e] = 1.f / (1.f + expf(-logit));
    }
}

// ---------------------------------------------------------------------------
extern "C" void kernel_launch(void* const* d_in, const int* in_sizes, int n_in,
                              void* d_out, int out_size, void* d_ws, size_t ws_size,
                              hipStream_t stream)
{
    const float* X   = (const float*)d_in[0];
    const float* adj = (const float*)d_in[1];
    const int*   e1  = (const int*)d_in[2];
    const int*   e2  = (const int*)d_in[3];
    const float* W   = (const float*)d_in[4];
    const float* W2  = (const float*)d_in[5];
    const float* W3  = (const float*)d_in[6];
    float* out = (float*)d_out;

    float*  ws    = (float*)d_ws;
    float*  a     = ws;                                  // NN
    float*  b     = a + NN;                              // NN
    float*  c     = b + NN;                              // 512
    ushort* Wt2   = (ushort*)(c + 512);                  // 16 panels * 8192
    ushort* XWt2  = Wt2  + (size_t)16 * 8192;            // 320 panels * 8192
    ushort* zb    = XWt2 + (size_t)320 * 8192;           // NN*HID
    ushort* Cpart = zb + (size_t)NN * HID;               // SKA*NN*HID bf16

    const dim3 blk(256);

    // W -> tiled bf16 panels (K=512 -> 16 panels)
    cvt_tiled<<<dim3(16), blk, 0, stream>>>(W, Wt2, IND);

    // zero pad panels 316..319 of XWt2
    zero_tail<<<dim3(4), blk, 0, stream>>>(XWt2);

    // XW panels = X @ W, fused panel epilogue (no split-K, no f32 round-trip)
    gemm_bt<true><<<dim3(79, 1), dim3(512), 0, stream>>>(
        X, Wt2, XWt2, NN, IND, IND, IND, 0);

    // Cpart = adj @ XW  (split-K = 8, direct bf16 store)
    gemm_bt<false><<<dim3(79, SKA), dim3(512), 0, stream>>>(
        adj, XWt2, Cpart, NN, NN, NN, KCHA, (size_t)NN * HID);

    // c = [u; v]
    k_uv<<<dim3(2), blk, 0, stream>>>(W2, W3, c);

    // reduce bf16 partials + z table + a,b
    k_node<<<dim3((NN * 64) / 256), blk, 0, stream>>>(Cpart, c, zb, a, b);

    // per-edge output (4 edges / wave)
    k_edge<<<dim3((2 * NE * 16) / 256), blk, 0, stream>>>(e1, e2, zb, a, b, W3, out);
}